// Round 12
// baseline (68.091 us; speedup 1.0000x reference)
//
#include <hip/hip_runtime.h>
#include <math.h>

static constexpr int N   = 4096;  // IN_SIZE
static constexpr int H   = 5;     // HID
static constexpr int NO  = 2048;  // OUT_SIZE
static constexpr float FEPS = 1e-4f;
static constexpr int RPB  = 8;         // X rows per block (phase A)
static constexpr int NBLK = N / RPB;   // 512 blocks
static constexpr int NR   = NO / NBLK; // 4 output rows per block (phase C)

#if __has_builtin(__builtin_amdgcn_rcpf)
__device__ __forceinline__ float frcp(float x) { return __builtin_amdgcn_rcpf(x); }
#else
__device__ __forceinline__ float frcp(float x) { return 1.0f / x; }
#endif
#if __has_builtin(__builtin_amdgcn_rsqf)
__device__ __forceinline__ float frsq(float x) { return __builtin_amdgcn_rsqf(x); }
#else
__device__ __forceinline__ float frsq(float x) { return 1.0f / sqrtf(x); }
#endif

__device__ __forceinline__ float wave_reduce(float v) {
#pragma unroll
    for (int o = 32; o > 0; o >>= 1) v += __shfl_down(v, o, 64);
    return v;
}

// Lane-parallel Jacobi rotation, compile-time (p,q). Lane L (<25) holds
// a = A[L/5][L%5], u = U[L/5][L%5].
#define JROT(p, q)                                                            \
    {                                                                         \
        const float apq = __shfl(a, (p) * 5 + (q), 64);                       \
        const float app = __shfl(a, (p) * 5 + (p), 64);                       \
        const float aqq = __shfl(a, (q) * 5 + (q), 64);                       \
        const bool  skip =                                                    \
            (apq * apq) <= (1e-26f * (app * app + aqq * aqq) + 1e-38f);       \
        const float theta = (aqq - app) * frcp(2.0f * apq);                   \
        const float tden  = fabsf(theta) + sqrtf(theta * theta + 1.0f);       \
        const float ttv   = ((theta >= 0.0f) ? 1.0f : -1.0f) * frcp(tden);    \
        float cc = frsq(ttv * ttv + 1.0f);                                    \
        float ss = ttv * cc;                                                  \
        cc = skip ? 1.0f : cc;                                                \
        ss = skip ? 0.0f : ss;                                                \
        {                                                                     \
            const int  pr   = ((r == (p)) ? (q) : ((r == (q)) ? (p) : r));    \
            const float prt = __shfl(a, pr * 5 + c, 64);                      \
            a = (r == (p)) ? (cc * a - ss * prt)                              \
                           : ((r == (q)) ? (ss * prt + cc * a) : a);          \
        }                                                                     \
        {                                                                     \
            const int  pc   = ((c == (p)) ? (q) : ((c == (q)) ? (p) : c));    \
            const float prt = __shfl(a, r * 5 + pc, 64);                      \
            a = (c == (p)) ? (cc * a - ss * prt)                              \
                           : ((c == (q)) ? (ss * prt + cc * a) : a);          \
            const float urt = __shfl(u, r * 5 + pc, 64);                      \
            u = (c == (p)) ? (cc * u - ss * urt)                              \
                           : ((c == (q)) ? (ss * urt + cc * u) : u);          \
        }                                                                     \
    }

// Single dispatch, 512 symmetric persistent blocks (2/CU).
// Handoff: Mp written with agent-scope sc1 atomic stores (completed at L3
// before sem add — vmcnt drained at the intervening __syncthreads); sem is
// a relaxed agent atomic. NO fences (R10->R11: removing them saved ~35us).
// NEW vs R11: the post-barrier Mp reduce uses PLAIN CACHED loads — the
// atomic (uncached) loads were 6.5M x 4B L2-bypass transactions ~ 420MB of
// L3 slot traffic ~ 40us. Plain loads are safe: no XCD L2 holds a stale Mp
// line this dispatch (sc1 stores don't allocate L2; launch-acquire
// invalidated), so first touch misses to L3, rest hit L2 (~205KB total).
__global__ __launch_bounds__(256, 2) void k_fused(const float* __restrict__ X,
                                                  const float* __restrict__ W1,
                                                  const float* __restrict__ W2,
                                                  float* __restrict__ Z,
                                                  float* __restrict__ Mp,
                                                  unsigned int* __restrict__ sem) {
    const int b  = blockIdx.x;
    const int t  = threadIdx.x;
    const int rb = b * RPB;
    const float4* W14 = reinterpret_cast<const float4*>(W1);

    // ---------- phase A: partial M = W1^T (X W1) over 8 rows ----------
    float acc[RPB][H];
#pragma unroll
    for (int r = 0; r < RPB; ++r)
#pragma unroll
        for (int a = 0; a < H; ++a) acc[r][a] = 0.f;

#pragma unroll
    for (int c = 0; c < 4; ++c) {
        const int j4 = c * 256 + t;
        float wf[20];
        {
            const float4 f0 = W14[5 * j4 + 0];
            const float4 f1 = W14[5 * j4 + 1];
            const float4 f2 = W14[5 * j4 + 2];
            const float4 f3 = W14[5 * j4 + 3];
            const float4 f4 = W14[5 * j4 + 4];
            wf[0]=f0.x;  wf[1]=f0.y;  wf[2]=f0.z;  wf[3]=f0.w;
            wf[4]=f1.x;  wf[5]=f1.y;  wf[6]=f1.z;  wf[7]=f1.w;
            wf[8]=f2.x;  wf[9]=f2.y;  wf[10]=f2.z; wf[11]=f2.w;
            wf[12]=f3.x; wf[13]=f3.y; wf[14]=f3.z; wf[15]=f3.w;
            wf[16]=f4.x; wf[17]=f4.y; wf[18]=f4.z; wf[19]=f4.w;
        }
#pragma unroll
        for (int r = 0; r < RPB; ++r) {
            const float4 x = reinterpret_cast<const float4*>(
                                 X + (size_t)(rb + r) * N)[j4];
#pragma unroll
            for (int a = 0; a < H; ++a)
                acc[r][a] += x.x * wf[a]      + x.y * wf[5 + a]
                           + x.z * wf[10 + a] + x.w * wf[15 + a];
        }
    }

    float pm[H][H];
#pragma unroll
    for (int a = 0; a < H; ++a)
#pragma unroll
        for (int bb = 0; bb < H; ++bb) pm[a][bb] = 0.f;
#pragma unroll
    for (int r = 0; r < RPB; ++r) {
        float w1r[H];
#pragma unroll
        for (int a = 0; a < H; ++a) w1r[a] = W1[(size_t)(rb + r) * H + a];
#pragma unroll
        for (int a = 0; a < H; ++a)
#pragma unroll
            for (int bb = 0; bb < H; ++bb) pm[a][bb] += w1r[a] * acc[r][bb];
    }

    __shared__ float sm[4][25];
    {
        const int lane = t & 63, wv = t >> 6;
#pragma unroll
        for (int a = 0; a < H; ++a)
#pragma unroll
            for (int bb = 0; bb < H; ++bb) {
                const float v = wave_reduce(pm[a][bb]);
                if (lane == 0) sm[wv][a * H + bb] = v;
            }
    }
    __syncthreads();
    if (t < 25) {
        const float v = sm[0][t] + sm[1][t] + sm[2][t] + sm[3][t];
        __hip_atomic_store(&Mp[b * 25 + t], v, __ATOMIC_RELAXED,
                           __HIP_MEMORY_SCOPE_AGENT);
    }
    __syncthreads();   // compiler drains vmcnt(0) here: Mp stores are AT L3
    if (t == 0) {
        __hip_atomic_fetch_add(sem, 1u, __ATOMIC_RELAXED,
                               __HIP_MEMORY_SCOPE_AGENT);
    }

    // ---------- overlap: preload phase-C W2 data (independent of sem) ----------
    const int i0 = b * NR;
    float4 w2j[2][H];
    float  wcol[NR][H];
#pragma unroll
    for (int hh = 0; hh < 2; ++hh) {
        const int jj = (hh * 256 + t) * 4;
#pragma unroll
        for (int m = 0; m < H; ++m)
            w2j[hh][m] = *reinterpret_cast<const float4*>(W2 + (size_t)m * NO + jj);
    }
#pragma unroll
    for (int r = 0; r < NR; ++r)
#pragma unroll
        for (int k = 0; k < H; ++k) wcol[r][k] = W2[(size_t)k * NO + i0 + r];

    // ---------- phase B: relaxed spin barrier (atomic polls go to L3) ----------
    if (t == 0) {
        while (__hip_atomic_load(sem, __ATOMIC_RELAXED,
                                 __HIP_MEMORY_SCOPE_AGENT) < (unsigned)NBLK)
            __builtin_amdgcn_s_sleep(8);
    }
    __syncthreads();

    __shared__ float sred[10][26];
    __shared__ float Msum[25];
    __shared__ float ys[25];

    // plain cached loads (L2-amplified): ~205KB total vs 420MB uncached
    if (t < 250) {
        const int e = t % 25, g = t / 25;
        float s = 0.f;
#pragma unroll 8
        for (int p = g; p < NBLK; p += 10) s += Mp[p * 25 + e];
        sred[g][e] = s;
    }
    __syncthreads();
    if (t < 25) {
        float s = 0.f;
#pragma unroll
        for (int g = 0; g < 10; ++g) s += sred[g][t];
        Msum[t] = s;
    }
    __syncthreads();

    if (t < 64) {
        const int r = t / 5, c = t % 5;
        const float m = (t < 25) ? Msum[t] : 0.f;
        float a = 0.f;
#pragma unroll
        for (int k = 0; k < H; ++k)
            a += __shfl(m, r * 5 + k, 64) * __shfl(m, c * 5 + k, 64);
        float u = (t < 25 && r == c) ? 1.0f : 0.0f;

        for (int sweep = 0; sweep < 6; ++sweep) {
            JROT(0, 1) JROT(0, 2) JROT(0, 3) JROT(0, 4) JROT(1, 2)
            JROT(1, 3) JROT(1, 4) JROT(2, 3) JROT(2, 4) JROT(3, 4)
        }

        const float ev = fmaxf(sqrtf(fmaxf(a, 0.0f)), FEPS);
        float yv = 0.f;
#pragma unroll
        for (int k = 0; k < H; ++k) {
            const float evk = __shfl(ev, 6 * k, 64);
            const float urk = __shfl(u, r * 5 + k, 64);
            const float uck = __shfl(u, c * 5 + k, 64);
            yv += evk * urk * uck;
        }
        if (t < 25) ys[t] = yv - ((r == c) ? FEPS : 0.f);
    }
    __syncthreads();

    // ---------- phase C: output rows i0..i0+3 ----------
    float cmat[NR][H];
#pragma unroll
    for (int r = 0; r < NR; ++r)
#pragma unroll
        for (int m = 0; m < H; ++m) {
            float s = 0.f;
#pragma unroll
            for (int k = 0; k < H; ++k) s += wcol[r][k] * ys[k * H + m];
            cmat[r][m] = s;
        }

#pragma unroll
    for (int hh = 0; hh < 2; ++hh) {
        const int jj = (hh * 256 + t) * 4;
#pragma unroll
        for (int r = 0; r < NR; ++r) {
            const int i = i0 + r;
            float zx = 0.f, zy = 0.f, zz = 0.f, zw = 0.f;
#pragma unroll
            for (int m = 0; m < H; ++m) {
                const float cm = cmat[r][m];
                zx += cm * w2j[hh][m].x;
                zy += cm * w2j[hh][m].y;
                zz += cm * w2j[hh][m].z;
                zw += cm * w2j[hh][m].w;
            }
            if (i >= jj && i < jj + 4) {
                if      (i == jj + 0) zx += FEPS;
                else if (i == jj + 1) zy += FEPS;
                else if (i == jj + 2) zz += FEPS;
                else                  zw += FEPS;
            }
            *reinterpret_cast<float4*>(Z + (size_t)i * NO + jj) =
                make_float4(zx, zy, zz, zw);
        }
    }
}

extern "C" void kernel_launch(void* const* d_in, const int* in_sizes, int n_in,
                              void* d_out, int out_size, void* d_ws, size_t ws_size,
                              hipStream_t stream) {
    const float* X  = (const float*)d_in[0];
    const float* W1 = (const float*)d_in[1];
    const float* W2 = (const float*)d_in[2];
    float* out = (float*)d_out;
    float* ws  = (float*)d_ws;

    float* Mp = ws;                                   // NBLK*25 floats
    unsigned int* sem = (unsigned int*)(ws + NBLK * 25);

    (void)hipMemsetAsync(sem, 0, sizeof(unsigned int), stream);
    hipLaunchKernelGGL(k_fused, dim3(NBLK), dim3(256), 0, stream,
                       X, W1, W2, out, Mp, sem);
}

// Round 13
// 41.044 us; speedup vs baseline: 1.6590x; 1.6590x over previous
//
#include <hip/hip_runtime.h>
#include <math.h>

static constexpr int N   = 4096;  // IN_SIZE
static constexpr int H   = 5;     // HID
static constexpr int NO  = 2048;  // OUT_SIZE
static constexpr float FEPS = 1e-4f;
static constexpr int NJC  = 4;          // j-chunks (1024 cols each)
static constexpr int NIG  = 128;        // i-groups (32 rows each)
static constexpr int RPB  = N / NIG;    // 32 rows per block
static constexpr int NBLK = NIG * NJC;  // 512 partial-M blocks
static constexpr int NCON = 256;        // k_out blocks
static constexpr int NR   = NO / NCON;  // 8 output rows per k_out block

#if __has_builtin(__builtin_amdgcn_rcpf)
__device__ __forceinline__ float frcp(float x) { return __builtin_amdgcn_rcpf(x); }
#else
__device__ __forceinline__ float frcp(float x) { return 1.0f / x; }
#endif
#if __has_builtin(__builtin_amdgcn_rsqf)
__device__ __forceinline__ float frsq(float x) { return __builtin_amdgcn_rsqf(x); }
#else
__device__ __forceinline__ float frsq(float x) { return 1.0f / sqrtf(x); }
#endif

__device__ __forceinline__ float wave_reduce(float v) {
#pragma unroll
    for (int o = 32; o > 0; o >>= 1) v += __shfl_down(v, o, 64);
    return v;
}

// K1: 2-D tiled partial of M[a][b] = sum_{i,j} W1[i,a] X[i,j] W1[j,b].
// Block (ig,jc): i in [ig*32,(ig+1)*32), j4 = jc*256 + t (one float4-col
// per thread). Each thread loads its 5 W1[j] float4s ONCE and reuses them
// across 32 rows (4x less gather traffic than the 1-D row version);
// X reads are perfectly coalesced, read-once. W1[i,*] row factors are
// block-uniform scalar loads.
__global__ __launch_bounds__(256) void k_xw1(const float* __restrict__ X,
                                             const float* __restrict__ W1,
                                             float* __restrict__ Mp) {
    const int b   = blockIdx.x;
    const int ig  = b >> 2;        // 128 i-groups
    const int jcb = b & 3;         // 4 j-chunks
    const int t   = threadIdx.x;
    const int j4  = jcb * 256 + t; // this thread's float4 column
    const float4* W14 = reinterpret_cast<const float4*>(W1);

    float wf[20];
    {
        const float4 f0 = W14[5 * j4 + 0];
        const float4 f1 = W14[5 * j4 + 1];
        const float4 f2 = W14[5 * j4 + 2];
        const float4 f3 = W14[5 * j4 + 3];
        const float4 f4 = W14[5 * j4 + 4];
        wf[0]=f0.x;  wf[1]=f0.y;  wf[2]=f0.z;  wf[3]=f0.w;
        wf[4]=f1.x;  wf[5]=f1.y;  wf[6]=f1.z;  wf[7]=f1.w;
        wf[8]=f2.x;  wf[9]=f2.y;  wf[10]=f2.z; wf[11]=f2.w;
        wf[12]=f3.x; wf[13]=f3.y; wf[14]=f3.z; wf[15]=f3.w;
        wf[16]=f4.x; wf[17]=f4.y; wf[18]=f4.z; wf[19]=f4.w;
    }

    float pm[H][H];
#pragma unroll
    for (int a = 0; a < H; ++a)
#pragma unroll
        for (int bb = 0; bb < H; ++bb) pm[a][bb] = 0.f;

    const int i0 = ig * RPB;
#pragma unroll 4
    for (int r = 0; r < RPB; ++r) {
        const float4 x = reinterpret_cast<const float4*>(
                             X + (size_t)(i0 + r) * N)[j4];
        float t5[H];
#pragma unroll
        for (int a = 0; a < H; ++a)
            t5[a] = x.x * wf[a]      + x.y * wf[5 + a]
                  + x.z * wf[10 + a] + x.w * wf[15 + a];
        float w1r[H];
#pragma unroll
        for (int a = 0; a < H; ++a) w1r[a] = W1[(size_t)(i0 + r) * H + a];
#pragma unroll
        for (int a = 0; a < H; ++a)
#pragma unroll
            for (int bb = 0; bb < H; ++bb) pm[a][bb] += w1r[a] * t5[bb];
    }

    __shared__ float sm[4][25];
    {
        const int lane = t & 63, wv = t >> 6;
#pragma unroll
        for (int a = 0; a < H; ++a)
#pragma unroll
            for (int bb = 0; bb < H; ++bb) {
                const float v = wave_reduce(pm[a][bb]);
                if (lane == 0) sm[wv][a * H + bb] = v;
            }
    }
    __syncthreads();
    if (t < 25)
        Mp[b * 25 + t] = sm[0][t] + sm[1][t] + sm[2][t] + sm[3][t];
}

// Lane-parallel Jacobi rotation, compile-time (p,q). Lane L (<25) holds
// a = A[L/5][L%5], u = U[L/5][L%5].
#define JROT(p, q)                                                            \
    {                                                                         \
        const float apq = __shfl(a, (p) * 5 + (q), 64);                       \
        const float app = __shfl(a, (p) * 5 + (p), 64);                       \
        const float aqq = __shfl(a, (q) * 5 + (q), 64);                       \
        const bool  skip =                                                    \
            (apq * apq) <= (1e-26f * (app * app + aqq * aqq) + 1e-38f);       \
        const float theta = (aqq - app) * frcp(2.0f * apq);                   \
        const float tden  = fabsf(theta) + sqrtf(theta * theta + 1.0f);       \
        const float ttv   = ((theta >= 0.0f) ? 1.0f : -1.0f) * frcp(tden);    \
        float cc = frsq(ttv * ttv + 1.0f);                                    \
        float ss = ttv * cc;                                                  \
        cc = skip ? 1.0f : cc;                                                \
        ss = skip ? 0.0f : ss;                                                \
        {                                                                     \
            const int  pr   = ((r == (p)) ? (q) : ((r == (q)) ? (p) : r));    \
            const float prt = __shfl(a, pr * 5 + c, 64);                      \
            a = (r == (p)) ? (cc * a - ss * prt)                              \
                           : ((r == (q)) ? (ss * prt + cc * a) : a);          \
        }                                                                     \
        {                                                                     \
            const int  pc   = ((c == (p)) ? (q) : ((c == (q)) ? (p) : c));    \
            const float prt = __shfl(a, r * 5 + pc, 64);                      \
            a = (c == (p)) ? (cc * a - ss * prt)                              \
                           : ((c == (q)) ? (ss * prt + cc * a) : a);          \
            const float urt = __shfl(u, r * 5 + pc, 64);                      \
            u = (c == (p)) ? (cc * u - ss * urt)                              \
                           : ((c == (q)) ? (ss * urt + cc * u) : u);          \
        }                                                                     \
    }

// K2: 256 blocks, NR=8 output rows each (R5's proven kernel, verbatim).
__global__ __launch_bounds__(256) void k_out(const float* __restrict__ Mp,
                                             const float* __restrict__ W2,
                                             float* __restrict__ Z) {
    __shared__ float sred[10][26];
    __shared__ float Msum[25];
    __shared__ float ys[25];
    const int t = threadIdx.x;

    if (t < 250) {
        const int e = t % 25, g = t / 25;
        float s = 0.f;
#pragma unroll 8
        for (int p = g; p < NBLK; p += 10) s += Mp[p * 25 + e];
        sred[g][e] = s;
    }
    __syncthreads();
    if (t < 25) {
        float s = 0.f;
#pragma unroll
        for (int g = 0; g < 10; ++g) s += sred[g][t];
        Msum[t] = s;
    }
    __syncthreads();

    if (t < 64) {
        const int r = t / 5, c = t % 5;
        const float m = (t < 25) ? Msum[t] : 0.f;
        float a = 0.f;
#pragma unroll
        for (int k = 0; k < H; ++k)
            a += __shfl(m, r * 5 + k, 64) * __shfl(m, c * 5 + k, 64);
        float u = (t < 25 && r == c) ? 1.0f : 0.0f;

        for (int sweep = 0; sweep < 6; ++sweep) {
            JROT(0, 1) JROT(0, 2) JROT(0, 3) JROT(0, 4) JROT(1, 2)
            JROT(1, 3) JROT(1, 4) JROT(2, 3) JROT(2, 4) JROT(3, 4)
        }

        const float ev = fmaxf(sqrtf(fmaxf(a, 0.0f)), FEPS);
        float yv = 0.f;
#pragma unroll
        for (int k = 0; k < H; ++k) {
            const float evk = __shfl(ev, 6 * k, 64);
            const float urk = __shfl(u, r * 5 + k, 64);
            const float uck = __shfl(u, c * 5 + k, 64);
            yv += evk * urk * uck;
        }
        if (t < 25) ys[t] = yv - ((r == c) ? FEPS : 0.f);
    }
    __syncthreads();

    const int i0 = blockIdx.x * NR;
    float cmat[NR][H];
#pragma unroll
    for (int r = 0; r < NR; ++r) {
        float wcol[H];
#pragma unroll
        for (int k = 0; k < H; ++k) wcol[k] = W2[(size_t)k * NO + i0 + r];
#pragma unroll
        for (int m = 0; m < H; ++m) {
            float s = 0.f;
#pragma unroll
            for (int k = 0; k < H; ++k) s += wcol[k] * ys[k * H + m];
            cmat[r][m] = s;
        }
    }

#pragma unroll
    for (int hh = 0; hh < 2; ++hh) {
        const int jj = (hh * 256 + t) * 4;
        float4 w2j[H];
#pragma unroll
        for (int m = 0; m < H; ++m)
            w2j[m] = *reinterpret_cast<const float4*>(W2 + (size_t)m * NO + jj);
#pragma unroll
        for (int r = 0; r < NR; ++r) {
            const int i = i0 + r;
            float zx = 0.f, zy = 0.f, zz = 0.f, zw = 0.f;
#pragma unroll
            for (int m = 0; m < H; ++m) {
                const float cm = cmat[r][m];
                zx += cm * w2j[m].x;
                zy += cm * w2j[m].y;
                zz += cm * w2j[m].z;
                zw += cm * w2j[m].w;
            }
            if (i >= jj && i < jj + 4) {
                if      (i == jj + 0) zx += FEPS;
                else if (i == jj + 1) zy += FEPS;
                else if (i == jj + 2) zz += FEPS;
                else                  zw += FEPS;
            }
            *reinterpret_cast<float4*>(Z + (size_t)i * NO + jj) =
                make_float4(zx, zy, zz, zw);
        }
    }
}

extern "C" void kernel_launch(void* const* d_in, const int* in_sizes, int n_in,
                              void* d_out, int out_size, void* d_ws, size_t ws_size,
                              hipStream_t stream) {
    const float* X  = (const float*)d_in[0];
    const float* W1 = (const float*)d_in[1];
    const float* W2 = (const float*)d_in[2];
    float* out = (float*)d_out;
    float* ws  = (float*)d_ws;

    float* Mp = ws;   // NBLK*25 floats

    hipLaunchKernelGGL(k_xw1, dim3(NBLK), dim3(256), 0, stream, X, W1, Mp);
    hipLaunchKernelGGL(k_out, dim3(NCON), dim3(256), 0, stream, Mp, W2, out);
}